// Round 1
// baseline (191.985 us; speedup 1.0000x reference)
//
#include <hip/hip_runtime.h>
#include <math.h>

#define B 256
#define D 512
#define S 196
#define SQ 49    // float4 quads per 196-float row
#define NCH 8

// ---------------- Kernel A: fused {g-GEMM head + p head + partial logits}.
// Grid B*8 = 2048 blocks x 256 thr, 8 blocks/CU.
// Head1: u = ctrl*w_attn staged in LDS.
// Head2: g[d] = sum_e u[e]*W[e,d] for this block's 64 d's, from L2-hot W panel.
//        Lane map: d-quad q = t&15, e = k*16 + (t>>4) -> W loads are 4x256B
//        coalesced, u_s[e] hits 4 distinct banks (broadcast, conflict-free).
//        Replaces separate K1 + gpart 8MB HBM round-trip + one launch.
// Head3: p_s[d] = mem*g + u  (b_concat is softmax-shift-invariant, dropped).
// Body : stream 64 kb rows (2 independent chains/wave), partial logits.
__global__ __launch_bounds__(256, 8) void k_fused_logits(
    const float* __restrict__ kb, const float* __restrict__ mem,
    const float* __restrict__ ctrl, const float* __restrict__ w_attn,
    const float* __restrict__ W, float* __restrict__ rai_part) {
    __shared__ float u_s[D];          // 2 KB
    __shared__ float gred[16][64];    // 4 KB
    __shared__ float p_s[64];
    __shared__ float part[4][S];      // 3.1 KB
    const int bid = blockIdx.x;
    const int b = bid >> 3, c = bid & 7;
    const int t = threadIdx.x;
    const int w = t >> 6, l = t & 63;

    u_s[t]       = ctrl[(size_t)b * D + t]       * w_attn[t];
    u_s[t + 256] = ctrl[(size_t)b * D + t + 256] * w_attn[t + 256];
    __syncthreads();

    {   // W panel: thread owns d-quad q, e = 16k + eg
        const int q = t & 15, eg = t >> 4;
        float4 g4 = {0.f, 0.f, 0.f, 0.f};
        const float* wbase = W + (size_t)c * 64 + 4 * q;
#pragma unroll 4
        for (int k = 0; k < 32; ++k) {
            const int e = k * 16 + eg;
            const float4 w4 = *(const float4*)(wbase + (size_t)e * D);
            const float uv = u_s[e];
            g4.x += uv * w4.x; g4.y += uv * w4.y;
            g4.z += uv * w4.z; g4.w += uv * w4.w;
        }
        *(float4*)&gred[eg][4 * q] = g4;
    }
    __syncthreads();
    if (t < 64) {
        float g = 0.f;
#pragma unroll
        for (int eg = 0; eg < 16; ++eg) g += gred[eg][t];
        const int d = c * 64 + t;
        p_s[t] = mem[(size_t)b * D + d] * g + u_s[d];
    }
    __syncthreads();

    const float* base = kb + (size_t)b * D * S + (size_t)c * 64 * S;
    if (l < SQ) {
        float4 acc0 = {0.f, 0.f, 0.f, 0.f}, acc1 = {0.f, 0.f, 0.f, 0.f};
        for (int i = 0; i < 8; ++i) {
            const int r0 = w * 16 + i, r1 = w * 16 + 8 + i;
            const float4 v0 = *(const float4*)(base + (size_t)r0 * S + 4 * l);
            const float4 v1 = *(const float4*)(base + (size_t)r1 * S + 4 * l);
            const float pv0 = p_s[r0], pv1 = p_s[r1];
            acc0.x += pv0 * v0.x; acc0.y += pv0 * v0.y;
            acc0.z += pv0 * v0.z; acc0.w += pv0 * v0.w;
            acc1.x += pv1 * v1.x; acc1.y += pv1 * v1.y;
            acc1.z += pv1 * v1.z; acc1.w += pv1 * v1.w;
        }
        part[w][4 * l + 0] = acc0.x + acc1.x;
        part[w][4 * l + 1] = acc0.y + acc1.y;
        part[w][4 * l + 2] = acc0.z + acc1.z;
        part[w][4 * l + 3] = acc0.w + acc1.w;
    }
    __syncthreads();
    if (t < S)
        rai_part[(size_t)bid * S + t] =
            (part[0][t] + part[1][t]) + (part[2][t] + part[3][t]);
}

// ---------------- Kernel B: softmax head + weighted sum. Grid 2048 x 256.
// Head: redundant (cheap, L2-hot) softmax from the 8 rai partials.
// Body: per-lane row partials go to a [64][49] LDS tile (stride 49 is odd ->
// <=2-way bank aliasing = free), then one transpose-reduce phase. Replaces
// 96 dependent shfl_xor ops/wave with ~29 DS wave-ops and makes the final
// store a single coalesced 256B write. kb re-read is L3-resident.
__global__ __launch_bounds__(256, 8) void k_wsum(
    const float* __restrict__ kb, const float* __restrict__ rai_part,
    float* __restrict__ out) {
    __shared__ float rvi_s[S];
    __shared__ float redm[4], reds[4];
    __shared__ float plds[64 * SQ];   // 12.5 KB
    __shared__ float red2[4][64];     // 1 KB
    const int bid = blockIdx.x;
    const int b = bid >> 3, c = bid & 7;
    const int t = threadIdx.x;
    const int w = t >> 6, l = t & 63;

    float rai = -INFINITY;
    if (t < S) {
        float v = 0.f;
#pragma unroll
        for (int k = 0; k < NCH; ++k)
            v += rai_part[((size_t)b * NCH + k) * S + t];
        rai = v;
    }
    float m = rai;
#pragma unroll
    for (int o = 1; o < 64; o <<= 1) m = fmaxf(m, __shfl_xor(m, o, 64));
    if (l == 0) redm[w] = m;
    __syncthreads();
    m = fmaxf(fmaxf(redm[0], redm[1]), fmaxf(redm[2], redm[3]));
    float ex = (t < S) ? __expf(rai - m) : 0.f;
    float sm = ex;
#pragma unroll
    for (int o = 1; o < 64; o <<= 1) sm += __shfl_xor(sm, o, 64);
    if (l == 0) reds[w] = sm;
    __syncthreads();
    const float li = (reds[0] + reds[1]) + (reds[2] + reds[3]);
    if (t < S) rvi_s[t] = ex / li;
    __syncthreads();

    float4 rv = {0.f, 0.f, 0.f, 0.f};
    if (l < SQ) rv = *(const float4*)&rvi_s[4 * l];
    const float* base = kb + (size_t)b * D * S + (size_t)c * 64 * S;
    if (l < SQ) {
#pragma unroll 2
        for (int i = 0; i < 8; ++i) {
            const int r0 = w * 16 + i, r1 = w * 16 + 8 + i;
            const float4 v0 = *(const float4*)(base + (size_t)r0 * S + 4 * l);
            const float4 v1 = *(const float4*)(base + (size_t)r1 * S + 4 * l);
            plds[r0 * SQ + l] =
                rv.x * v0.x + rv.y * v0.y + rv.z * v0.z + rv.w * v0.w;
            plds[r1 * SQ + l] =
                rv.x * v1.x + rv.y * v1.y + rv.z * v1.z + rv.w * v1.w;
        }
    }
    __syncthreads();
    {   // transpose-reduce: thread (seg, row) sums its 12-13 quad partials
        const int row = t & 63, seg = t >> 6;
        const int j0 = (seg * SQ) >> 2, j1 = ((seg + 1) * SQ) >> 2;
        float a = 0.f;
        for (int j = j0; j < j1; ++j) a += plds[row * SQ + j];
        red2[seg][row] = a;
    }
    __syncthreads();
    if (t < 64)
        out[(size_t)b * D + c * 64 + t] =
            (red2[0][t] + red2[1][t]) + (red2[2][t] + red2[3][t]);
}

extern "C" void kernel_launch(void* const* d_in, const int* in_sizes, int n_in,
                              void* d_out, int out_size, void* d_ws, size_t ws_size,
                              hipStream_t stream) {
    const float* mem  = (const float*)d_in[0];  // [B, d]
    const float* ctrl = (const float*)d_in[1];  // [B, d]
    const float* kb   = (const float*)d_in[2];  // [B, d, S]
    const float* W    = (const float*)d_in[3];  // [d, d]
    // d_in[4] = b_concat: softmax-shift-invariant, unused
    const float* wat  = (const float*)d_in[5];  // [d]
    float* out = (float*)d_out;                 // [B, d]

    float* rai_part = (float*)d_ws;             // 2048*S*4 = 1.6 MB

    k_fused_logits<<<B * NCH, 256, 0, stream>>>(kb, mem, ctrl, wat, W, rai_part);
    k_wsum        <<<B * NCH, 256, 0, stream>>>(kb, rai_part, out);
}